// Round 14
// baseline (1787.634 us; speedup 1.0000x reference)
//
#include <hip/hip_runtime.h>
#include <math.h>
#include <stdint.h>

constexpr int BATCH  = 512;
constexpr int NNODE  = 100;
constexpr int HDIM   = 256;
constexpr int NHEAD  = 8;
constexpr int DHEAD  = 32;
constexpr int NLAYER = 3;
constexpr int FDIM   = 512;
constexpr int MTOK   = BATCH * NNODE;   // 51200
constexpr int RLEN   = 200;             // route row length = 1 + 199

typedef unsigned short u16;
typedef unsigned int   u32;
typedef __attribute__((ext_vector_type(8))) short bf16x8;   // 8 bf16 (4 VGPRs)
typedef __attribute__((ext_vector_type(4))) float f32x4;    // MFMA acc

static __device__ __forceinline__ float wave_sum(float v) {
#pragma unroll
    for (int o = 32; o; o >>= 1) v += __shfl_xor(v, o);
    return v;
}
static __device__ __forceinline__ float wave_max(float v) {
#pragma unroll
    for (int o = 32; o; o >>= 1) v = fmaxf(v, __shfl_xor(v, o));
    return v;
}

// f32 -> bf16 (RNE) and back
static __device__ __forceinline__ u16 f2bf(float f) {
    u32 u = __float_as_uint(f);
    u += 0x7FFFu + ((u >> 16) & 1u);
    return (u16)(u >> 16);
}
static __device__ __forceinline__ float bf2f(u16 h) {
    return __uint_as_float(((u32)h) << 16);
}
static __device__ __forceinline__ u32 pk2(u16 a, u16 b) { return (u32)a | ((u32)b << 16); }

// split 8 f32 into bf16 hi/lo and store 16B each to LDS
static __device__ __forceinline__ void split_store8(const float* v, u16* ph, u16* pl) {
    u16 h[8], l[8];
#pragma unroll
    for (int j = 0; j < 8; ++j) {
        h[j] = f2bf(v[j]);
        l[j] = f2bf(v[j] - bf2f(h[j]));
    }
    uint4 uh = make_uint4(pk2(h[0], h[1]), pk2(h[2], h[3]), pk2(h[4], h[5]), pk2(h[6], h[7]));
    uint4 ul = make_uint4(pk2(l[0], l[1]), pk2(l[2], l[3]), pk2(l[4], l[5]), pk2(l[6], l[7]));
    *reinterpret_cast<uint4*>(ph) = uh;
    *reinterpret_cast<uint4*>(pl) = ul;
}

// ---------------- node embedding: x = node_feats @ W_node + b_node ----------------
__global__ void k_embed(const float* __restrict__ nf, const float* __restrict__ W,
                        const float* __restrict__ bias, float* __restrict__ x) {
    int idx = blockIdx.x * 256 + threadIdx.x;   // over MTOK*HDIM
    int row = idx >> 8;
    int col = idx & 255;
    float a0 = nf[row * 3 + 0], a1 = nf[row * 3 + 1], a2 = nf[row * 3 + 2];
    x[idx] = fmaf(a0, W[col], fmaf(a1, W[256 + col], fmaf(a2, W[512 + col], bias[col])));
}

// ------------- MFMA GEMM, 3-term bf16 split: C = op(A@W + bias (+res)) -------------
// 128x128 block tile, 4 waves (2x2), each wave 4x4 frags of 16x16x32 bf16 MFMA.
// K-permutation safety: A and B frags use the SAME (lane>>4)*8+j k-mapping, so any
// HW k-permutation cancels in the dot product. C/D layout per guide (m89/m91):
// col = lane&15, row = (lane>>4)*4 + reg.
// A split in-register during staging; W split+transposed in-register (L2-hit reads).
// No prefetch state across the compute loop (R4/R7/R10 spill lesson).
template<int KSIZE, int NSIZE, bool RELU, bool RES>
__global__ __launch_bounds__(256) void k_mfma(const float* __restrict__ A, int lda,
                                              const float* __restrict__ W,
                                              const float* __restrict__ bias,
                                              const float* __restrict__ res,
                                              float* __restrict__ C) {
    __shared__ u16 Ash[128][40];   // [row][k], +8 pad: 2-way max on frag reads
    __shared__ u16 Asl[128][40];
    __shared__ u16 Bsh[128][40];   // [col][k]
    __shared__ u16 Bsl[128][40];
    const int t    = threadIdx.x;
    const int lane = t & 63, wv = t >> 6;
    const int wr   = wv >> 1, wc = wv & 1;      // wave 2x2 grid
    const int m0   = blockIdx.y * 128, n0 = blockIdx.x * 128;
    const int sr   = t >> 1;                    // staging row/col 0..127
    const int kh   = (t & 1) * 16;              // staging k-half
    const int lr   = lane & 15, ks = (lane >> 4) * 8;

    f32x4 acc[4][4] = {};

    for (int kc = 0; kc < KSIZE; kc += 32) {
        // global loads (regs only, before barrier)
        float av[16];
        const float* ap = &A[(size_t)(m0 + sr) * lda + kc + kh];
#pragma unroll
        for (int j = 0; j < 4; ++j) {
            float4 v = *reinterpret_cast<const float4*>(ap + 4 * j);
            av[4 * j + 0] = v.x; av[4 * j + 1] = v.y;
            av[4 * j + 2] = v.z; av[4 * j + 3] = v.w;
        }
        float wvv[16];
        const float* wp = &W[(size_t)(kc + kh) * NSIZE + n0 + sr];
#pragma unroll
        for (int j = 0; j < 16; ++j) wvv[j] = wp[(size_t)j * NSIZE];

        __syncthreads();   // previous tile's frag reads done
        split_store8(av,     &Ash[sr][kh],     &Asl[sr][kh]);
        split_store8(av + 8, &Ash[sr][kh + 8], &Asl[sr][kh + 8]);
        split_store8(wvv,     &Bsh[sr][kh],     &Bsl[sr][kh]);
        split_store8(wvv + 8, &Bsh[sr][kh + 8], &Bsl[sr][kh + 8]);
        __syncthreads();   // tile staged

        bf16x8 afh[4], afl[4], bfh[4], bfl[4];
#pragma unroll
        for (int i = 0; i < 4; ++i) {
            afh[i] = *reinterpret_cast<const bf16x8*>(&Ash[wr * 64 + i * 16 + lr][ks]);
            afl[i] = *reinterpret_cast<const bf16x8*>(&Asl[wr * 64 + i * 16 + lr][ks]);
            bfh[i] = *reinterpret_cast<const bf16x8*>(&Bsh[wc * 64 + i * 16 + lr][ks]);
            bfl[i] = *reinterpret_cast<const bf16x8*>(&Bsl[wc * 64 + i * 16 + lr][ks]);
        }
#pragma unroll
        for (int mi = 0; mi < 4; ++mi)
#pragma unroll
        for (int ni = 0; ni < 4; ++ni) {
            acc[mi][ni] = __builtin_amdgcn_mfma_f32_16x16x32_bf16(afh[mi], bfh[ni], acc[mi][ni], 0, 0, 0);
            acc[mi][ni] = __builtin_amdgcn_mfma_f32_16x16x32_bf16(afh[mi], bfl[ni], acc[mi][ni], 0, 0, 0);
            acc[mi][ni] = __builtin_amdgcn_mfma_f32_16x16x32_bf16(afl[mi], bfh[ni], acc[mi][ni], 0, 0, 0);
        }
    }

    // epilogue: C/D layout col=lane&15, row=(lane>>4)*4+q
#pragma unroll
    for (int ni = 0; ni < 4; ++ni) {
        const int col = n0 + wc * 64 + ni * 16 + lr;
        const float bb = bias[col];
#pragma unroll
        for (int mi = 0; mi < 4; ++mi) {
            const int row0 = m0 + wr * 64 + mi * 16 + (lane >> 4) * 4;
#pragma unroll
            for (int q = 0; q < 4; ++q) {
                size_t off = (size_t)(row0 + q) * NSIZE + col;
                float o = acc[mi][ni][q] + bb;
                if constexpr (RES) o += res[off];
                if constexpr (RELU) o = fmaxf(o, 0.f);
                C[off] = o;
            }
        }
    }
}

// deterministic 32-dot, identical accumulation order in both passes
static __device__ __forceinline__ float dot32(const float* __restrict__ q,
                                              const float* __restrict__ k) {
    float a = 0.f, b = 0.f;
#pragma unroll
    for (int d = 0; d < 32; d += 2) {
        a = fmaf(q[d],     k[d],     a);
        b = fmaf(q[d + 1], k[d + 1], b);
    }
    return a + b;
}

// ---------------- attention (R6-proven): one wave per (b,h); K/V staged in LDS ----
__global__ __launch_bounds__(64) void k_attn(const float* __restrict__ qkv,
                                             float* __restrict__ out) {
    __shared__ alignas(16) float ks[NNODE * 32];
    __shared__ alignas(16) float vs[NNODE * 32];
    const int b    = blockIdx.x >> 3;
    const int h    = blockIdx.x & 7;
    const int lane = threadIdx.x;
    const float* __restrict__ base = qkv + (size_t)b * NNODE * 768 + h * DHEAD;

    for (int idx = lane; idx < NNODE * 8; idx += 64) {
        int j = idx >> 3, c = idx & 7;
        float4 kv = *reinterpret_cast<const float4*>(base + (size_t)j * 768 + 256 + c * 4);
        float4 vv = *reinterpret_cast<const float4*>(base + (size_t)j * 768 + 512 + c * 4);
        *reinterpret_cast<float4*>(&ks[j * 32 + c * 4]) = kv;
        *reinterpret_cast<float4*>(&vs[j * 32 + c * 4]) = vv;
    }
    __syncthreads();

    const int  i1   = lane;
    const bool has2 = lane < (NNODE - 64);
    const int  i2   = has2 ? lane + 64 : 0;

    float q1[32], q2[32];
    {
        const float* p1 = base + (size_t)i1 * 768;
        const float* p2 = base + (size_t)i2 * 768;
#pragma unroll
        for (int c = 0; c < 8; ++c) {
            float4 a = *reinterpret_cast<const float4*>(p1 + c * 4);
            float4 e = *reinterpret_cast<const float4*>(p2 + c * 4);
            q1[4 * c + 0] = a.x; q1[4 * c + 1] = a.y; q1[4 * c + 2] = a.z; q1[4 * c + 3] = a.w;
            q2[4 * c + 0] = e.x; q2[4 * c + 1] = e.y; q2[4 * c + 2] = e.z; q2[4 * c + 3] = e.w;
        }
    }
    constexpr float scale = 0.17677669529663687f;

    float m1 = -INFINITY, m2 = -INFINITY;
    for (int j = 0; j < NNODE; ++j) {
        const float* kp = &ks[j * 32];
        float kk[32];
#pragma unroll
        for (int c = 0; c < 8; ++c) {
            float4 kv = *reinterpret_cast<const float4*>(kp + c * 4);
            kk[4 * c + 0] = kv.x; kk[4 * c + 1] = kv.y; kk[4 * c + 2] = kv.z; kk[4 * c + 3] = kv.w;
        }
        m1 = fmaxf(m1, dot32(q1, kk) * scale);
        m2 = fmaxf(m2, dot32(q2, kk) * scale);
    }

    float l1 = 0.f, l2 = 0.f;
    float o1[32] = {}, o2[32] = {};
    for (int j = 0; j < NNODE; ++j) {
        const float* kp = &ks[j * 32];
        const float* vp = &vs[j * 32];
        float kk[32];
#pragma unroll
        for (int c = 0; c < 8; ++c) {
            float4 kv = *reinterpret_cast<const float4*>(kp + c * 4);
            kk[4 * c + 0] = kv.x; kk[4 * c + 1] = kv.y; kk[4 * c + 2] = kv.z; kk[4 * c + 3] = kv.w;
        }
        float s1 = dot32(q1, kk) * scale;
        float s2 = dot32(q2, kk) * scale;
        float p1 = __expf(s1 - m1);
        float p2 = __expf(s2 - m2);
        l1 += p1;
        l2 += p2;
#pragma unroll
        for (int c = 0; c < 8; ++c) {
            float4 vv = *reinterpret_cast<const float4*>(vp + c * 4);
            o1[4 * c + 0] = fmaf(p1, vv.x, o1[4 * c + 0]);
            o1[4 * c + 1] = fmaf(p1, vv.y, o1[4 * c + 1]);
            o1[4 * c + 2] = fmaf(p1, vv.z, o1[4 * c + 2]);
            o1[4 * c + 3] = fmaf(p1, vv.w, o1[4 * c + 3]);
            o2[4 * c + 0] = fmaf(p2, vv.x, o2[4 * c + 0]);
            o2[4 * c + 1] = fmaf(p2, vv.y, o2[4 * c + 1]);
            o2[4 * c + 2] = fmaf(p2, vv.z, o2[4 * c + 2]);
            o2[4 * c + 3] = fmaf(p2, vv.w, o2[4 * c + 3]);
        }
    }

    const float inv1 = 1.f / l1;
    float* op1 = out + ((size_t)b * NNODE + i1) * 768 + h * DHEAD;
#pragma unroll
    for (int c = 0; c < 8; ++c) {
        float4 w = make_float4(o1[4 * c + 0] * inv1, o1[4 * c + 1] * inv1,
                               o1[4 * c + 2] * inv1, o1[4 * c + 3] * inv1);
        *reinterpret_cast<float4*>(op1 + c * 4) = w;
    }
    if (has2) {
        const float inv2 = 1.f / l2;
        float* op2 = out + ((size_t)b * NNODE + i2) * 768 + h * DHEAD;
#pragma unroll
        for (int c = 0; c < 8; ++c) {
            float4 w = make_float4(o2[4 * c + 0] * inv2, o2[4 * c + 1] * inv2,
                                   o2[4 * c + 2] * inv2, o2[4 * c + 3] * inv2);
            *reinterpret_cast<float4*>(op2 + c * 4) = w;
        }
    }
}

// ---------------- in-place LayerNorm over H=256, one wave per row ----------------
__global__ __launch_bounds__(256) void k_ln(float* __restrict__ x, const float* __restrict__ sc,
                                            const float* __restrict__ bp) {
    const int row = blockIdx.x * 4 + (threadIdx.x >> 6);
    const int lane = threadIdx.x & 63;
    float* rp = &x[(size_t)row * HDIM + lane * 4];
    float4 v = *reinterpret_cast<const float4*>(rp);
    float mean = wave_sum(v.x + v.y + v.z + v.w) * (1.f / 256.f);
    float d0 = v.x - mean, d1 = v.y - mean, d2 = v.z - mean, d3 = v.w - mean;
    float var = wave_sum(d0 * d0 + d1 * d1 + d2 * d2 + d3 * d3) * (1.f / 256.f);
    float inv = 1.f / sqrtf(var + 1e-5f);
    float4 sv = *reinterpret_cast<const float4*>(&sc[lane * 4]);
    float4 bv = *reinterpret_cast<const float4*>(&bp[lane * 4]);
    float4 ov;
    ov.x = fmaf(d0 * inv, sv.x, bv.x);
    ov.y = fmaf(d1 * inv, sv.y, bv.y);
    ov.z = fmaf(d2 * inv, sv.z, bv.z);
    ov.w = fmaf(d3 * inv, sv.w, bv.w);
    *reinterpret_cast<float4*>(rp) = ov;
}

// ---------------- Gram: S[b] = x[b] @ x[b]^T  (one block per batch, pure f32) -----
__global__ __launch_bounds__(256) void k_gram(const float* __restrict__ x, float* __restrict__ S) {
    __shared__ alignas(16) float xs[16][128];
    const int b = blockIdx.x;
    const int t = threadIdx.x, tx = t & 15, ty = t >> 4;
    const int li = t >> 1, lko = (t & 1) * 8;
    float acc[8][8] = {};
    for (int kc = 0; kc < HDIM; kc += 16) {
        float va[8] = {0.f, 0.f, 0.f, 0.f, 0.f, 0.f, 0.f, 0.f};
        if (li < NNODE) {
            const float* p = &x[((size_t)b * NNODE + li) * HDIM + kc + lko];
            float4 u0 = *reinterpret_cast<const float4*>(p);
            float4 u1 = *reinterpret_cast<const float4*>(p + 4);
            va[0] = u0.x; va[1] = u0.y; va[2] = u0.z; va[3] = u0.w;
            va[4] = u1.x; va[5] = u1.y; va[6] = u1.z; va[7] = u1.w;
        }
        __syncthreads();
#pragma unroll
        for (int m = 0; m < 8; ++m) xs[lko + m][li] = va[m];
        __syncthreads();
#pragma unroll
        for (int k = 0; k < 16; ++k) {
            float ai[8], bj[8];
#pragma unroll
            for (int a = 0; a < 8; ++a) ai[a] = xs[k][ty + 16 * a];
#pragma unroll
            for (int c = 0; c < 8; ++c) bj[c] = xs[k][tx + 16 * c];
#pragma unroll
            for (int a = 0; a < 8; ++a)
#pragma unroll
                for (int c = 0; c < 8; ++c)
                    acc[a][c] = fmaf(ai[a], bj[c], acc[a][c]);
        }
    }
#pragma unroll
    for (int a = 0; a < 8; ++a) {
        int i = ty + 16 * a;
        if (i < NNODE) {
#pragma unroll
            for (int c = 0; c < 8; ++c) {
                int j = tx + 16 * c;
                if (j < NNODE) S[(size_t)b * NNODE * NNODE + (size_t)i * NNODE + j] = acc[a][c];
            }
        }
    }
}

// ---------------- routing decode (R11-proven): one wave per batch; S[b] in LDS ----
__global__ __launch_bounds__(64, 1) void k_route(const float* __restrict__ S,
                                                 const float* __restrict__ demand,
                                                 const float* __restrict__ capacity,
                                                 const float* __restrict__ gumbel,
                                                 float* __restrict__ out, int nsteps) {
    __shared__ alignas(16) float Sl[NNODE * NNODE];   // 40 KB
    const int b = blockIdx.x;
    const int lane = threadIdx.x;
    const float* Sb = S + (size_t)b * NNODE * NNODE;
    for (int i = lane; i < NNODE * NNODE / 4; i += 64)
        *reinterpret_cast<float4*>(&Sl[i * 4]) = *reinterpret_cast<const float4*>(&Sb[i * 4]);
    __syncthreads();

    const int j1 = lane, j2 = lane + 64;
    const bool v2 = (j2 < NNODE);
    const float d1 = demand[(size_t)b * NNODE + j1];
    const float d2 = v2 ? demand[(size_t)b * NNODE + j2] : 0.f;
    bool vis1 = (j1 == 0), vis2 = false;
    float cap = capacity[b];
    int cur = 0;
    float lp = 0.f;
    float* route = out + (size_t)b * RLEN;
    if (lane == 0) route[0] = 0.f;

    float g1 = gumbel[(size_t)b * NNODE + j1];
    float g2 = v2 ? gumbel[(size_t)b * NNODE + j2] : 0.f;

    for (int s = 0; s < nsteps; ++s) {
        float ng1 = 0.f, ng2 = 0.f;
        if (s + 1 < nsteps) {
            const float* gn = gumbel + ((size_t)(s + 1) * BATCH + b) * NNODE;
            ng1 = gn[j1];
            ng2 = v2 ? gn[j2] : 0.f;
        }
        bool f1 = (!vis1) && (d1 <= cap);
        bool f2 = v2 && (!vis2) && (d2 <= cap);
        if (__ballot(f1 || f2) == 0ULL) {
            if (lane == 0) route[1 + s] = 0.f;
            g1 = ng1; g2 = ng2;
            continue;
        }
        const float* sr = &Sl[cur * NNODE];
        float m1 = f1 ? sr[j1] : -1e9f;
        float m2 = f2 ? sr[j2] : -1e9f;
        float k1 = m1 + g1;
        float k2 = v2 ? (m2 + g2) : -INFINITY;
        float bk; int bi;
        if (k1 >= k2) { bk = k1; bi = j1; } else { bk = k2; bi = j2; }
#pragma unroll
        for (int off = 32; off; off >>= 1) {
            float ok = __shfl_xor(bk, off);
            int   oi = __shfl_xor(bi, off);
            if (ok > bk || (ok == bk && oi < bi)) { bk = ok; bi = oi; }
        }
        const int choice = bi;
        float mx = wave_max(fmaxf(m1, v2 ? m2 : -1e9f));
        float e = __expf(m1 - mx) + (v2 ? __expf(m2 - mx) : 0.f);
        e = wave_sum(e);
        float msel = __shfl((choice < 64) ? m1 : m2, choice & 63);
        float dsel = __shfl((choice < 64) ? d1 : d2, choice & 63);
        lp += msel - mx - __logf(e);
        if (j1 == choice) vis1 = true;
        if (j2 == choice) vis2 = true;
        cap -= dsel;
        cur = choice;
        if (lane == 0) route[1 + s] = (float)choice;
        g1 = ng1; g2 = ng2;
    }
    if (lane == 0) out[(size_t)BATCH * RLEN + b] = lp;
}

extern "C" void kernel_launch(void* const* d_in, const int* in_sizes, int n_in,
                              void* d_out, int out_size, void* d_ws, size_t ws_size,
                              hipStream_t stream) {
    const float* node_feats = (const float*)d_in[0];
    const float* demand     = (const float*)d_in[1];
    const float* capacity   = (const float*)d_in[2];
    const float* gumbel     = (const float*)d_in[3];
    const float* W_node     = (const float*)d_in[4];
    const float* b_node     = (const float*)d_in[5];
    const float* qkv_w      = (const float*)d_in[6];
    const float* qkv_b      = (const float*)d_in[7];
    const float* out_w      = (const float*)d_in[8];
    const float* out_b      = (const float*)d_in[9];
    const float* ln1_s      = (const float*)d_in[10];
    const float* ln1_b      = (const float*)d_in[11];
    const float* w1         = (const float*)d_in[12];
    const float* b1         = (const float*)d_in[13];
    const float* w2         = (const float*)d_in[14];
    const float* b2         = (const float*)d_in[15];
    const float* ln2_s      = (const float*)d_in[16];
    const float* ln2_b      = (const float*)d_in[17];
    const int gsteps = in_sizes[3] / (BATCH * NNODE);   // 199

    float* x    = (float*)d_ws;                       // [MTOK][256]
    float* buf1 = x + (size_t)MTOK * HDIM;            // [MTOK][768]
    float* S    = buf1;                               // reuse after encoder
    float* out  = (float*)d_out;

    k_embed<<<MTOK * HDIM / 256, 256, 0, stream>>>(node_feats, W_node, b_node, x);

    for (int l = 0; l < NLAYER; ++l) {
        // qkv = x @ qkv_w + qkv_b            [MTOK,768]
        k_mfma<256, 768, false, false><<<dim3(6, MTOK / 128), 256, 0, stream>>>(
            x, 256, qkv_w + (size_t)l * 256 * 768, qkv_b + (size_t)l * 768, nullptr, buf1);
        // attention (o written into q-slice of buf1, row stride 768)
        k_attn<<<BATCH * NHEAD, 64, 0, stream>>>(buf1, buf1);
        // x = x + o @ out_w + out_b
        k_mfma<256, 256, false, true><<<dim3(2, MTOK / 128), 256, 0, stream>>>(
            buf1, 768, out_w + (size_t)l * 256 * 256, out_b + (size_t)l * 256, x, x);
        k_ln<<<MTOK / 4, 256, 0, stream>>>(x, ln1_s + (size_t)l * 256, ln1_b + (size_t)l * 256);
        // h = relu(x @ w1 + b1)              [MTOK,512]
        k_mfma<256, 512, true, false><<<dim3(4, MTOK / 128), 256, 0, stream>>>(
            x, 256, w1 + (size_t)l * 256 * 512, b1 + (size_t)l * 512, nullptr, buf1);
        // x = x + h @ w2 + b2
        k_mfma<512, 256, false, true><<<dim3(2, MTOK / 128), 256, 0, stream>>>(
            buf1, 512, w2 + (size_t)l * 512 * 256, b2 + (size_t)l * 256, x, x);
        k_ln<<<MTOK / 4, 256, 0, stream>>>(x, ln2_s + (size_t)l * 256, ln2_b + (size_t)l * 256);
    }

    k_gram<<<BATCH, 256, 0, stream>>>(x, S);
    k_route<<<BATCH, 64, 0, stream>>>(S, demand, capacity, gumbel, out, gsteps);
    (void)n_in; (void)out_size; (void)ws_size;
}

// Round 15
// 1648.206 us; speedup vs baseline: 1.0846x; 1.0846x over previous
//
#include <hip/hip_runtime.h>
#include <math.h>
#include <stdint.h>

constexpr int BATCH  = 512;
constexpr int NNODE  = 100;
constexpr int HDIM   = 256;
constexpr int NHEAD  = 8;
constexpr int DHEAD  = 32;
constexpr int NLAYER = 3;
constexpr int FDIM   = 512;
constexpr int MTOK   = BATCH * NNODE;   // 51200
constexpr int RLEN   = 200;             // route row length = 1 + 199

typedef unsigned short u16;
typedef unsigned int   u32;
typedef __attribute__((ext_vector_type(8))) short bf16x8;   // 8 bf16 (4 VGPRs)
typedef __attribute__((ext_vector_type(4))) float f32x4;    // MFMA acc

static __device__ __forceinline__ float wave_sum(float v) {
#pragma unroll
    for (int o = 32; o; o >>= 1) v += __shfl_xor(v, o);
    return v;
}
static __device__ __forceinline__ float wave_max(float v) {
#pragma unroll
    for (int o = 32; o; o >>= 1) v = fmaxf(v, __shfl_xor(v, o));
    return v;
}

// f32 -> bf16 (RNE) and back
static __device__ __forceinline__ u16 f2bf(float f) {
    u32 u = __float_as_uint(f);
    u += 0x7FFFu + ((u >> 16) & 1u);
    return (u16)(u >> 16);
}
static __device__ __forceinline__ float bf2f(u16 h) {
    return __uint_as_float(((u32)h) << 16);
}
static __device__ __forceinline__ u32 pk2(u16 a, u16 b) { return (u32)a | ((u32)b << 16); }

// split 8 f32 into bf16 hi/lo and store 16B each to LDS
static __device__ __forceinline__ void split_store8(const float* v, u16* ph, u16* pl) {
    u16 h[8], l[8];
#pragma unroll
    for (int j = 0; j < 8; ++j) {
        h[j] = f2bf(v[j]);
        l[j] = f2bf(v[j] - bf2f(h[j]));
    }
    uint4 uh = make_uint4(pk2(h[0], h[1]), pk2(h[2], h[3]), pk2(h[4], h[5]), pk2(h[6], h[7]));
    uint4 ul = make_uint4(pk2(l[0], l[1]), pk2(l[2], l[3]), pk2(l[4], l[5]), pk2(l[6], l[7]));
    *reinterpret_cast<uint4*>(ph) = uh;
    *reinterpret_cast<uint4*>(pl) = ul;
}

// ---------------- node embedding: x = node_feats @ W_node + b_node ----------------
__global__ void k_embed(const float* __restrict__ nf, const float* __restrict__ W,
                        const float* __restrict__ bias, float* __restrict__ x) {
    int idx = blockIdx.x * 256 + threadIdx.x;   // over MTOK*HDIM
    int row = idx >> 8;
    int col = idx & 255;
    float a0 = nf[row * 3 + 0], a1 = nf[row * 3 + 1], a2 = nf[row * 3 + 2];
    x[idx] = fmaf(a0, W[col], fmaf(a1, W[256 + col], fmaf(a2, W[512 + col], bias[col])));
}

// ------- weight pre-split: W[K][N] f32 -> WhT/WlT [N][K] bf16 (once per launch) -----
// Eliminates the 400x-redundant per-block W split + strided scalar loads in k_mfma.
// Same f2bf RNE values as the in-kernel split -> GEMM outputs bit-identical.
__global__ __launch_bounds__(256) void k_wsplit(const float* __restrict__ W,
                                                u16* __restrict__ dh, u16* __restrict__ dl,
                                                int K, int N) {
    const int id = blockIdx.x * 256 + threadIdx.x;    // over N * (K/8)
    const int l  = blockIdx.y;
    if (id >= N * (K / 8)) return;
    const int n  = id % N;              // consecutive lanes -> consecutive n (coalesced reads)
    const int k0 = (id / N) * 8;
    const float* src = W + (size_t)l * K * N;
    u16* ph = dh + (size_t)l * N * K + (size_t)n * K + k0;
    u16* pl = dl + (size_t)l * N * K + (size_t)n * K + k0;
    u16 h[8], lo[8];
#pragma unroll
    for (int j = 0; j < 8; ++j) {
        float f = src[(size_t)(k0 + j) * N + n];
        h[j]  = f2bf(f);
        lo[j] = f2bf(f - bf2f(h[j]));
    }
    *reinterpret_cast<uint4*>(ph) = make_uint4(pk2(h[0], h[1]), pk2(h[2], h[3]),
                                               pk2(h[4], h[5]), pk2(h[6], h[7]));
    *reinterpret_cast<uint4*>(pl) = make_uint4(pk2(lo[0], lo[1]), pk2(lo[2], lo[3]),
                                               pk2(lo[4], lo[5]), pk2(lo[6], lo[7]));
}

// ------------- MFMA GEMM, 3-term bf16 split: C = op(A@W + bias (+res)) -------------
// 128x128 block tile, 4 waves (2x2), each wave 4x4 frags of 16x16x32 bf16 MFMA.
// A split in-register during staging (R14-proven); W read PRE-SPLIT ([N][K] bf16 hi/lo)
// via 16B vector copies — zero conversion VALU, no strided loads.
// No prefetch state across the compute loop (R4/R7/R10 spill lesson).
template<int KSIZE, int NSIZE, bool RELU, bool RES>
__global__ __launch_bounds__(256) void k_mfma(const float* __restrict__ A, int lda,
                                              const u16* __restrict__ WhT,
                                              const u16* __restrict__ WlT,
                                              const float* __restrict__ bias,
                                              const float* __restrict__ res,
                                              float* __restrict__ C) {
    __shared__ u16 Ash[128][40];   // [row][k], +8 pad
    __shared__ u16 Asl[128][40];
    __shared__ u16 Bsh[128][40];   // [col][k]
    __shared__ u16 Bsl[128][40];
    const int t    = threadIdx.x;
    const int lane = t & 63, wv = t >> 6;
    const int wr   = wv >> 1, wc = wv & 1;      // wave 2x2 grid
    const int m0   = blockIdx.y * 128, n0 = blockIdx.x * 128;
    const int sr   = t >> 1;                    // staging row/col 0..127
    const int kh   = (t & 1) * 16;              // staging k-half
    const int lr   = lane & 15, ks = (lane >> 4) * 8;

    f32x4 acc[4][4] = {};

    for (int kc = 0; kc < KSIZE; kc += 32) {
        // global loads (regs only, before barrier)
        float av[16];
        const float* ap = &A[(size_t)(m0 + sr) * lda + kc + kh];
#pragma unroll
        for (int j = 0; j < 4; ++j) {
            float4 v = *reinterpret_cast<const float4*>(ap + 4 * j);
            av[4 * j + 0] = v.x; av[4 * j + 1] = v.y;
            av[4 * j + 2] = v.z; av[4 * j + 3] = v.w;
        }
        const u16* wph = &WhT[(size_t)(n0 + sr) * KSIZE + kc + kh];
        const u16* wpl = &WlT[(size_t)(n0 + sr) * KSIZE + kc + kh];
        uint4 bh0 = *reinterpret_cast<const uint4*>(wph);
        uint4 bh1 = *reinterpret_cast<const uint4*>(wph + 8);
        uint4 bl0 = *reinterpret_cast<const uint4*>(wpl);
        uint4 bl1 = *reinterpret_cast<const uint4*>(wpl + 8);

        __syncthreads();   // previous tile's frag reads done
        split_store8(av,     &Ash[sr][kh],     &Asl[sr][kh]);
        split_store8(av + 8, &Ash[sr][kh + 8], &Asl[sr][kh + 8]);
        *reinterpret_cast<uint4*>(&Bsh[sr][kh])     = bh0;
        *reinterpret_cast<uint4*>(&Bsh[sr][kh + 8]) = bh1;
        *reinterpret_cast<uint4*>(&Bsl[sr][kh])     = bl0;
        *reinterpret_cast<uint4*>(&Bsl[sr][kh + 8]) = bl1;
        __syncthreads();   // tile staged

        bf16x8 afh[4], afl[4], bfh[4], bfl[4];
#pragma unroll
        for (int i = 0; i < 4; ++i) {
            afh[i] = *reinterpret_cast<const bf16x8*>(&Ash[wr * 64 + i * 16 + lr][ks]);
            afl[i] = *reinterpret_cast<const bf16x8*>(&Asl[wr * 64 + i * 16 + lr][ks]);
            bfh[i] = *reinterpret_cast<const bf16x8*>(&Bsh[wc * 64 + i * 16 + lr][ks]);
            bfl[i] = *reinterpret_cast<const bf16x8*>(&Bsl[wc * 64 + i * 16 + lr][ks]);
        }
#pragma unroll
        for (int mi = 0; mi < 4; ++mi)
#pragma unroll
        for (int ni = 0; ni < 4; ++ni) {
            acc[mi][ni] = __builtin_amdgcn_mfma_f32_16x16x32_bf16(afh[mi], bfh[ni], acc[mi][ni], 0, 0, 0);
            acc[mi][ni] = __builtin_amdgcn_mfma_f32_16x16x32_bf16(afh[mi], bfl[ni], acc[mi][ni], 0, 0, 0);
            acc[mi][ni] = __builtin_amdgcn_mfma_f32_16x16x32_bf16(afl[mi], bfh[ni], acc[mi][ni], 0, 0, 0);
        }
    }

    // epilogue: C/D layout col=lane&15, row=(lane>>4)*4+q
#pragma unroll
    for (int ni = 0; ni < 4; ++ni) {
        const int col = n0 + wc * 64 + ni * 16 + lr;
        const float bb = bias[col];
#pragma unroll
        for (int mi = 0; mi < 4; ++mi) {
            const int row0 = m0 + wr * 64 + mi * 16 + (lane >> 4) * 4;
#pragma unroll
            for (int q = 0; q < 4; ++q) {
                size_t off = (size_t)(row0 + q) * NSIZE + col;
                float o = acc[mi][ni][q] + bb;
                if constexpr (RES) o += res[off];
                if constexpr (RELU) o = fmaxf(o, 0.f);
                C[off] = o;
            }
        }
    }
}

// deterministic 32-dot, identical accumulation order in both passes
static __device__ __forceinline__ float dot32(const float* __restrict__ q,
                                              const float* __restrict__ k) {
    float a = 0.f, b = 0.f;
#pragma unroll
    for (int d = 0; d < 32; d += 2) {
        a = fmaf(q[d],     k[d],     a);
        b = fmaf(q[d + 1], k[d + 1], b);
    }
    return a + b;
}

// ---------------- attention (R6-proven): one wave per (b,h); K/V staged in LDS ----
__global__ __launch_bounds__(64) void k_attn(const float* __restrict__ qkv,
                                             float* __restrict__ out) {
    __shared__ alignas(16) float ks[NNODE * 32];
    __shared__ alignas(16) float vs[NNODE * 32];
    const int b    = blockIdx.x >> 3;
    const int h    = blockIdx.x & 7;
    const int lane = threadIdx.x;
    const float* __restrict__ base = qkv + (size_t)b * NNODE * 768 + h * DHEAD;

    for (int idx = lane; idx < NNODE * 8; idx += 64) {
        int j = idx >> 3, c = idx & 7;
        float4 kv = *reinterpret_cast<const float4*>(base + (size_t)j * 768 + 256 + c * 4);
        float4 vv = *reinterpret_cast<const float4*>(base + (size_t)j * 768 + 512 + c * 4);
        *reinterpret_cast<float4*>(&ks[j * 32 + c * 4]) = kv;
        *reinterpret_cast<float4*>(&vs[j * 32 + c * 4]) = vv;
    }
    __syncthreads();

    const int  i1   = lane;
    const bool has2 = lane < (NNODE - 64);
    const int  i2   = has2 ? lane + 64 : 0;

    float q1[32], q2[32];
    {
        const float* p1 = base + (size_t)i1 * 768;
        const float* p2 = base + (size_t)i2 * 768;
#pragma unroll
        for (int c = 0; c < 8; ++c) {
            float4 a = *reinterpret_cast<const float4*>(p1 + c * 4);
            float4 e = *reinterpret_cast<const float4*>(p2 + c * 4);
            q1[4 * c + 0] = a.x; q1[4 * c + 1] = a.y; q1[4 * c + 2] = a.z; q1[4 * c + 3] = a.w;
            q2[4 * c + 0] = e.x; q2[4 * c + 1] = e.y; q2[4 * c + 2] = e.z; q2[4 * c + 3] = e.w;
        }
    }
    constexpr float scale = 0.17677669529663687f;

    float m1 = -INFINITY, m2 = -INFINITY;
    for (int j = 0; j < NNODE; ++j) {
        const float* kp = &ks[j * 32];
        float kk[32];
#pragma unroll
        for (int c = 0; c < 8; ++c) {
            float4 kv = *reinterpret_cast<const float4*>(kp + c * 4);
            kk[4 * c + 0] = kv.x; kk[4 * c + 1] = kv.y; kk[4 * c + 2] = kv.z; kk[4 * c + 3] = kv.w;
        }
        m1 = fmaxf(m1, dot32(q1, kk) * scale);
        m2 = fmaxf(m2, dot32(q2, kk) * scale);
    }

    float l1 = 0.f, l2 = 0.f;
    float o1[32] = {}, o2[32] = {};
    for (int j = 0; j < NNODE; ++j) {
        const float* kp = &ks[j * 32];
        const float* vp = &vs[j * 32];
        float kk[32];
#pragma unroll
        for (int c = 0; c < 8; ++c) {
            float4 kv = *reinterpret_cast<const float4*>(kp + c * 4);
            kk[4 * c + 0] = kv.x; kk[4 * c + 1] = kv.y; kk[4 * c + 2] = kv.z; kk[4 * c + 3] = kv.w;
        }
        float s1 = dot32(q1, kk) * scale;
        float s2 = dot32(q2, kk) * scale;
        float p1 = __expf(s1 - m1);
        float p2 = __expf(s2 - m2);
        l1 += p1;
        l2 += p2;
#pragma unroll
        for (int c = 0; c < 8; ++c) {
            float4 vv = *reinterpret_cast<const float4*>(vp + c * 4);
            o1[4 * c + 0] = fmaf(p1, vv.x, o1[4 * c + 0]);
            o1[4 * c + 1] = fmaf(p1, vv.y, o1[4 * c + 1]);
            o1[4 * c + 2] = fmaf(p1, vv.z, o1[4 * c + 2]);
            o1[4 * c + 3] = fmaf(p1, vv.w, o1[4 * c + 3]);
            o2[4 * c + 0] = fmaf(p2, vv.x, o2[4 * c + 0]);
            o2[4 * c + 1] = fmaf(p2, vv.y, o2[4 * c + 1]);
            o2[4 * c + 2] = fmaf(p2, vv.z, o2[4 * c + 2]);
            o2[4 * c + 3] = fmaf(p2, vv.w, o2[4 * c + 3]);
        }
    }

    const float inv1 = 1.f / l1;
    float* op1 = out + ((size_t)b * NNODE + i1) * 768 + h * DHEAD;
#pragma unroll
    for (int c = 0; c < 8; ++c) {
        float4 w = make_float4(o1[4 * c + 0] * inv1, o1[4 * c + 1] * inv1,
                               o1[4 * c + 2] * inv1, o1[4 * c + 3] * inv1);
        *reinterpret_cast<float4*>(op1 + c * 4) = w;
    }
    if (has2) {
        const float inv2 = 1.f / l2;
        float* op2 = out + ((size_t)b * NNODE + i2) * 768 + h * DHEAD;
#pragma unroll
        for (int c = 0; c < 8; ++c) {
            float4 w = make_float4(o2[4 * c + 0] * inv2, o2[4 * c + 1] * inv2,
                                   o2[4 * c + 2] * inv2, o2[4 * c + 3] * inv2);
            *reinterpret_cast<float4*>(op2 + c * 4) = w;
        }
    }
}

// ---------------- in-place LayerNorm over H=256, one wave per row ----------------
__global__ __launch_bounds__(256) void k_ln(float* __restrict__ x, const float* __restrict__ sc,
                                            const float* __restrict__ bp) {
    const int row = blockIdx.x * 4 + (threadIdx.x >> 6);
    const int lane = threadIdx.x & 63;
    float* rp = &x[(size_t)row * HDIM + lane * 4];
    float4 v = *reinterpret_cast<const float4*>(rp);
    float mean = wave_sum(v.x + v.y + v.z + v.w) * (1.f / 256.f);
    float d0 = v.x - mean, d1 = v.y - mean, d2 = v.z - mean, d3 = v.w - mean;
    float var = wave_sum(d0 * d0 + d1 * d1 + d2 * d2 + d3 * d3) * (1.f / 256.f);
    float inv = 1.f / sqrtf(var + 1e-5f);
    float4 sv = *reinterpret_cast<const float4*>(&sc[lane * 4]);
    float4 bv = *reinterpret_cast<const float4*>(&bp[lane * 4]);
    float4 ov;
    ov.x = fmaf(d0 * inv, sv.x, bv.x);
    ov.y = fmaf(d1 * inv, sv.y, bv.y);
    ov.z = fmaf(d2 * inv, sv.z, bv.z);
    ov.w = fmaf(d3 * inv, sv.w, bv.w);
    *reinterpret_cast<float4*>(rp) = ov;
}

// ---------------- Gram: S[b] = x[b] @ x[b]^T  (one block per batch, pure f32) -----
__global__ __launch_bounds__(256) void k_gram(const float* __restrict__ x, float* __restrict__ S) {
    __shared__ alignas(16) float xs[16][128];
    const int b = blockIdx.x;
    const int t = threadIdx.x, tx = t & 15, ty = t >> 4;
    const int li = t >> 1, lko = (t & 1) * 8;
    float acc[8][8] = {};
    for (int kc = 0; kc < HDIM; kc += 16) {
        float va[8] = {0.f, 0.f, 0.f, 0.f, 0.f, 0.f, 0.f, 0.f};
        if (li < NNODE) {
            const float* p = &x[((size_t)b * NNODE + li) * HDIM + kc + lko];
            float4 u0 = *reinterpret_cast<const float4*>(p);
            float4 u1 = *reinterpret_cast<const float4*>(p + 4);
            va[0] = u0.x; va[1] = u0.y; va[2] = u0.z; va[3] = u0.w;
            va[4] = u1.x; va[5] = u1.y; va[6] = u1.z; va[7] = u1.w;
        }
        __syncthreads();
#pragma unroll
        for (int m = 0; m < 8; ++m) xs[lko + m][li] = va[m];
        __syncthreads();
#pragma unroll
        for (int k = 0; k < 16; ++k) {
            float ai[8], bj[8];
#pragma unroll
            for (int a = 0; a < 8; ++a) ai[a] = xs[k][ty + 16 * a];
#pragma unroll
            for (int c = 0; c < 8; ++c) bj[c] = xs[k][tx + 16 * c];
#pragma unroll
            for (int a = 0; a < 8; ++a)
#pragma unroll
                for (int c = 0; c < 8; ++c)
                    acc[a][c] = fmaf(ai[a], bj[c], acc[a][c]);
        }
    }
#pragma unroll
    for (int a = 0; a < 8; ++a) {
        int i = ty + 16 * a;
        if (i < NNODE) {
#pragma unroll
            for (int c = 0; c < 8; ++c) {
                int j = tx + 16 * c;
                if (j < NNODE) S[(size_t)b * NNODE * NNODE + (size_t)i * NNODE + j] = acc[a][c];
            }
        }
    }
}

// ---------------- routing decode: merged single-butterfly reduction ----------------
// One 6-level butterfly carries (key, idx, msel, dsel, m, s): 6 shuffles/level issued
// concurrently (one LDS wait) replaces 3 separate reductions + 2 broadcasts
// (~20 dependent ds_swizzle ops -> 6). Argmax comparisons and tie-break are
// bit-identical to the proven code; m/s give the exact log-softmax terms.
__global__ __launch_bounds__(64, 1) void k_route(const float* __restrict__ S,
                                                 const float* __restrict__ demand,
                                                 const float* __restrict__ capacity,
                                                 const float* __restrict__ gumbel,
                                                 float* __restrict__ out, int nsteps) {
    __shared__ alignas(16) float Sl[NNODE * NNODE];   // 40 KB
    const int b = blockIdx.x;
    const int lane = threadIdx.x;
    const float* Sb = S + (size_t)b * NNODE * NNODE;
    for (int i = lane; i < NNODE * NNODE / 4; i += 64)
        *reinterpret_cast<float4*>(&Sl[i * 4]) = *reinterpret_cast<const float4*>(&Sb[i * 4]);
    __syncthreads();

    const int j1 = lane, j2 = lane + 64;
    const bool v2 = (j2 < NNODE);
    const float d1 = demand[(size_t)b * NNODE + j1];
    const float d2 = v2 ? demand[(size_t)b * NNODE + j2] : 0.f;
    bool vis1 = (j1 == 0), vis2 = false;
    float cap = capacity[b];
    int cur = 0;
    float lp = 0.f;
    float* route = out + (size_t)b * RLEN;
    if (lane == 0) route[0] = 0.f;

    float g1 = gumbel[(size_t)b * NNODE + j1];
    float g2 = v2 ? gumbel[(size_t)b * NNODE + j2] : 0.f;

    for (int s = 0; s < nsteps; ++s) {
        float ng1 = 0.f, ng2 = 0.f;
        if (s + 1 < nsteps) {   // next step's gumbel issues now; hides under this step
            const float* gn = gumbel + ((size_t)(s + 1) * BATCH + b) * NNODE;
            ng1 = gn[j1];
            ng2 = v2 ? gn[j2] : 0.f;
        }
        bool f1 = (!vis1) && (d1 <= cap);
        bool f2 = v2 && (!vis2) && (d2 <= cap);
        if (__ballot(f1 || f2) == 0ULL) {
            if (lane == 0) route[1 + s] = 0.f;
            g1 = ng1; g2 = ng2;
            continue;
        }
        const float* sr = &Sl[cur * NNODE];
        float m1 = f1 ? sr[j1] : -1e9f;
        float m2 = f2 ? sr[j2] : -1e9f;
        // local combine of (j1, j2): identical tie-break (prefer lower index)
        float k1 = m1 + g1;
        float k2 = v2 ? (m2 + g2) : -INFINITY;
        float key, msel, dsel;
        int idx;
        if (k1 >= k2) { key = k1; idx = j1; msel = m1; dsel = d1; }
        else          { key = k2; idx = j2; msel = m2; dsel = d2; }
        float m = fmaxf(m1, m2);                   // m2 already -1e9 when !f2/!v2
        float sum = __expf(m1 - m) + (v2 ? __expf(m2 - m) : 0.f);
        // merged butterfly: argmax + online-softmax in one pass
#pragma unroll
        for (int off = 32; off; off >>= 1) {
            float key2  = __shfl_xor(key, off);
            int   idx2  = __shfl_xor(idx, off);
            float msel2 = __shfl_xor(msel, off);
            float dsel2 = __shfl_xor(dsel, off);
            float mm2   = __shfl_xor(m, off);
            float ss2   = __shfl_xor(sum, off);
            if (key2 > key || (key2 == key && idx2 < idx)) {
                key = key2; idx = idx2; msel = msel2; dsel = dsel2;
            }
            float mn = fmaxf(m, mm2);
            sum = sum * __expf(m - mn) + ss2 * __expf(mm2 - mn);
            m = mn;
        }
        const int choice = idx;   // uniform across wave
        lp += msel - m - __logf(sum);
        if (j1 == choice) vis1 = true;
        if (j2 == choice) vis2 = true;
        cap -= dsel;
        cur = choice;
        if (lane == 0) route[1 + s] = (float)choice;
        g1 = ng1; g2 = ng2;
    }
    if (lane == 0) out[(size_t)BATCH * RLEN + b] = lp;
}

extern "C" void kernel_launch(void* const* d_in, const int* in_sizes, int n_in,
                              void* d_out, int out_size, void* d_ws, size_t ws_size,
                              hipStream_t stream) {
    const float* node_feats = (const float*)d_in[0];
    const float* demand     = (const float*)d_in[1];
    const float* capacity   = (const float*)d_in[2];
    const float* gumbel     = (const float*)d_in[3];
    const float* W_node     = (const float*)d_in[4];
    const float* b_node     = (const float*)d_in[5];
    const float* qkv_w      = (const float*)d_in[6];
    const float* qkv_b      = (const float*)d_in[7];
    const float* out_w      = (const float*)d_in[8];
    const float* out_b      = (const float*)d_in[9];
    const float* ln1_s      = (const float*)d_in[10];
    const float* ln1_b      = (const float*)d_in[11];
    const float* w1         = (const float*)d_in[12];
    const float* b1         = (const float*)d_in[13];
    const float* w2         = (const float*)d_in[14];
    const float* b2         = (const float*)d_in[15];
    const float* ln2_s      = (const float*)d_in[16];
    const float* ln2_b      = (const float*)d_in[17];
    const int gsteps = in_sizes[3] / (BATCH * NNODE);   // 199

    float* x    = (float*)d_ws;                       // [MTOK][256]  52 MB
    float* buf1 = x + (size_t)MTOK * HDIM;            // [MTOK][768]  157 MB
    float* S    = buf1;                               // reuse after encoder
    // pre-split transposed weights at ws tail (+6.3 MB)
    u16* qkvTh = (u16*)(buf1 + (size_t)MTOK * 768);
    u16* qkvTl = qkvTh + (size_t)3 * 768 * 256;
    u16* prjTh = qkvTl + (size_t)3 * 768 * 256;
    u16* prjTl = prjTh + (size_t)3 * 256 * 256;
    u16* f1Th  = prjTl + (size_t)3 * 256 * 256;
    u16* f1Tl  = f1Th  + (size_t)3 * 512 * 256;
    u16* f2Th  = f1Tl  + (size_t)3 * 512 * 256;
    u16* f2Tl  = f2Th  + (size_t)3 * 256 * 512;
    float* out = (float*)d_out;

    // one-time weight splits (per launch; deterministic)
    k_wsplit<<<dim3((768 * 32 + 255) / 256, 3), 256, 0, stream>>>(qkv_w, qkvTh, qkvTl, 256, 768);
    k_wsplit<<<dim3((256 * 32 + 255) / 256, 3), 256, 0, stream>>>(out_w, prjTh, prjTl, 256, 256);
    k_wsplit<<<dim3((512 * 32 + 255) / 256, 3), 256, 0, stream>>>(w1, f1Th, f1Tl, 256, 512);
    k_wsplit<<<dim3((256 * 64 + 255) / 256, 3), 256, 0, stream>>>(w2, f2Th, f2Tl, 512, 256);

    k_embed<<<MTOK * HDIM / 256, 256, 0, stream>>>(node_feats, W_node, b_node, x);

    for (int l = 0; l < NLAYER; ++l) {
        // qkv = x @ qkv_w + qkv_b            [MTOK,768]
        k_mfma<256, 768, false, false><<<dim3(6, MTOK / 128), 256, 0, stream>>>(
            x, 256, qkvTh + (size_t)l * 768 * 256, qkvTl + (size_t)l * 768 * 256,
            qkv_b + (size_t)l * 768, nullptr, buf1);
        // attention (o written into q-slice of buf1, row stride 768)
        k_attn<<<BATCH * NHEAD, 64, 0, stream>>>(buf1, buf1);
        // x = x + o @ out_w + out_b
        k_mfma<256, 256, false, true><<<dim3(2, MTOK / 128), 256, 0, stream>>>(
            buf1, 768, prjTh + (size_t)l * 256 * 256, prjTl + (size_t)l * 256 * 256,
            out_b + (size_t)l * 256, x, x);
        k_ln<<<MTOK / 4, 256, 0, stream>>>(x, ln1_s + (size_t)l * 256, ln1_b + (size_t)l * 256);
        // h = relu(x @ w1 + b1)              [MTOK,512]
        k_mfma<256, 512, true, false><<<dim3(4, MTOK / 128), 256, 0, stream>>>(
            x, 256, f1Th + (size_t)l * 512 * 256, f1Tl + (size_t)l * 512 * 256,
            b1 + (size_t)l * 512, nullptr, buf1);
        // x = x + h @ w2 + b2
        k_mfma<512, 256, false, true><<<dim3(2, MTOK / 128), 256, 0, stream>>>(
            buf1, 512, f2Th + (size_t)l * 256 * 512, f2Tl + (size_t)l * 256 * 512,
            b2 + (size_t)l * 256, x, x);
        k_ln<<<MTOK / 4, 256, 0, stream>>>(x, ln2_s + (size_t)l * 256, ln2_b + (size_t)l * 256);
    }

    k_gram<<<BATCH, 256, 0, stream>>>(x, S);
    k_route<<<BATCH, 64, 0, stream>>>(S, demand, capacity, gumbel, out, gsteps);
    (void)n_in; (void)out_size; (void)ws_size;
}

// Round 16
// 1647.353 us; speedup vs baseline: 1.0852x; 1.0005x over previous
//
#include <hip/hip_runtime.h>
#include <math.h>
#include <stdint.h>

constexpr int BATCH  = 512;
constexpr int NNODE  = 100;
constexpr int HDIM   = 256;
constexpr int NHEAD  = 8;
constexpr int DHEAD  = 32;
constexpr int NLAYER = 3;
constexpr int FDIM   = 512;
constexpr int MTOK   = BATCH * NNODE;   // 51200
constexpr int RLEN   = 200;             // route row length = 1 + 199

typedef unsigned short u16;
typedef unsigned int   u32;
typedef __attribute__((ext_vector_type(8))) short bf16x8;   // 8 bf16 (4 VGPRs)
typedef __attribute__((ext_vector_type(4))) float f32x4;    // MFMA acc

static __device__ __forceinline__ float wave_sum(float v) {
#pragma unroll
    for (int o = 32; o; o >>= 1) v += __shfl_xor(v, o);
    return v;
}
static __device__ __forceinline__ float wave_max(float v) {
#pragma unroll
    for (int o = 32; o; o >>= 1) v = fmaxf(v, __shfl_xor(v, o));
    return v;
}

// f32 -> bf16 (RNE) and back
static __device__ __forceinline__ u16 f2bf(float f) {
    u32 u = __float_as_uint(f);
    u += 0x7FFFu + ((u >> 16) & 1u);
    return (u16)(u >> 16);
}
static __device__ __forceinline__ float bf2f(u16 h) {
    return __uint_as_float(((u32)h) << 16);
}
static __device__ __forceinline__ u32 pk2(u16 a, u16 b) { return (u32)a | ((u32)b << 16); }

// split 8 f32 into bf16 hi/lo and store 16B each to LDS
static __device__ __forceinline__ void split_store8(const float* v, u16* ph, u16* pl) {
    u16 h[8], l[8];
#pragma unroll
    for (int j = 0; j < 8; ++j) {
        h[j] = f2bf(v[j]);
        l[j] = f2bf(v[j] - bf2f(h[j]));
    }
    uint4 uh = make_uint4(pk2(h[0], h[1]), pk2(h[2], h[3]), pk2(h[4], h[5]), pk2(h[6], h[7]));
    uint4 ul = make_uint4(pk2(l[0], l[1]), pk2(l[2], l[3]), pk2(l[4], l[5]), pk2(l[6], l[7]));
    *reinterpret_cast<uint4*>(ph) = uh;
    *reinterpret_cast<uint4*>(pl) = ul;
}

// DPP / swizzle cross-lane helpers (VALU-latency for intra-row levels)
// quad_perm xor1 = 0xB1, xor2 = 0x4E; row_ror:4 = 0x124, row_ror:8 = 0x128.
template<int CTRL>
static __device__ __forceinline__ float fdpp(float v) {
    return __int_as_float(__builtin_amdgcn_update_dpp(0, __float_as_int(v), CTRL, 0xF, 0xF, true));
}
template<int CTRL>
static __device__ __forceinline__ int idpp(int v) {
    return __builtin_amdgcn_update_dpp(0, v, CTRL, 0xF, 0xF, true);
}
static __device__ __forceinline__ float fswz16(float v) {
    return __int_as_float(__builtin_amdgcn_ds_swizzle(__float_as_int(v), 0x401F));  // xor16
}
static __device__ __forceinline__ int iswz16(int v) {
    return __builtin_amdgcn_ds_swizzle(v, 0x401F);
}

// ---------------- node embedding: x = node_feats @ W_node + b_node ----------------
__global__ void k_embed(const float* __restrict__ nf, const float* __restrict__ W,
                        const float* __restrict__ bias, float* __restrict__ x) {
    int idx = blockIdx.x * 256 + threadIdx.x;   // over MTOK*HDIM
    int row = idx >> 8;
    int col = idx & 255;
    float a0 = nf[row * 3 + 0], a1 = nf[row * 3 + 1], a2 = nf[row * 3 + 2];
    x[idx] = fmaf(a0, W[col], fmaf(a1, W[256 + col], fmaf(a2, W[512 + col], bias[col])));
}

// ------- weight pre-split: W[K][N] f32 -> WhT/WlT [N][K] bf16 (once per launch) -----
__global__ __launch_bounds__(256) void k_wsplit(const float* __restrict__ W,
                                                u16* __restrict__ dh, u16* __restrict__ dl,
                                                int K, int N) {
    const int id = blockIdx.x * 256 + threadIdx.x;    // over N * (K/8)
    const int l  = blockIdx.y;
    if (id >= N * (K / 8)) return;
    const int n  = id % N;
    const int k0 = (id / N) * 8;
    const float* src = W + (size_t)l * K * N;
    u16* ph = dh + (size_t)l * N * K + (size_t)n * K + k0;
    u16* pl = dl + (size_t)l * N * K + (size_t)n * K + k0;
    u16 h[8], lo[8];
#pragma unroll
    for (int j = 0; j < 8; ++j) {
        float f = src[(size_t)(k0 + j) * N + n];
        h[j]  = f2bf(f);
        lo[j] = f2bf(f - bf2f(h[j]));
    }
    *reinterpret_cast<uint4*>(ph) = make_uint4(pk2(h[0], h[1]), pk2(h[2], h[3]),
                                               pk2(h[4], h[5]), pk2(h[6], h[7]));
    *reinterpret_cast<uint4*>(pl) = make_uint4(pk2(lo[0], lo[1]), pk2(lo[2], lo[3]),
                                               pk2(lo[4], lo[5]), pk2(lo[6], lo[7]));
}

// ------------- MFMA GEMM, 3-term bf16 split (R15-proven) ---------------------------
template<int KSIZE, int NSIZE, bool RELU, bool RES>
__global__ __launch_bounds__(256) void k_mfma(const float* __restrict__ A, int lda,
                                              const u16* __restrict__ WhT,
                                              const u16* __restrict__ WlT,
                                              const float* __restrict__ bias,
                                              const float* __restrict__ res,
                                              float* __restrict__ C) {
    __shared__ u16 Ash[128][40];   // [row][k], +8 pad
    __shared__ u16 Asl[128][40];
    __shared__ u16 Bsh[128][40];   // [col][k]
    __shared__ u16 Bsl[128][40];
    const int t    = threadIdx.x;
    const int lane = t & 63, wv = t >> 6;
    const int wr   = wv >> 1, wc = wv & 1;      // wave 2x2 grid
    const int m0   = blockIdx.y * 128, n0 = blockIdx.x * 128;
    const int sr   = t >> 1;                    // staging row/col 0..127
    const int kh   = (t & 1) * 16;              // staging k-half
    const int lr   = lane & 15, ks = (lane >> 4) * 8;

    f32x4 acc[4][4] = {};

    for (int kc = 0; kc < KSIZE; kc += 32) {
        // global loads (regs only, before barrier)
        float av[16];
        const float* ap = &A[(size_t)(m0 + sr) * lda + kc + kh];
#pragma unroll
        for (int j = 0; j < 4; ++j) {
            float4 v = *reinterpret_cast<const float4*>(ap + 4 * j);
            av[4 * j + 0] = v.x; av[4 * j + 1] = v.y;
            av[4 * j + 2] = v.z; av[4 * j + 3] = v.w;
        }
        const u16* wph = &WhT[(size_t)(n0 + sr) * KSIZE + kc + kh];
        const u16* wpl = &WlT[(size_t)(n0 + sr) * KSIZE + kc + kh];
        uint4 bh0 = *reinterpret_cast<const uint4*>(wph);
        uint4 bh1 = *reinterpret_cast<const uint4*>(wph + 8);
        uint4 bl0 = *reinterpret_cast<const uint4*>(wpl);
        uint4 bl1 = *reinterpret_cast<const uint4*>(wpl + 8);

        __syncthreads();   // previous tile's frag reads done
        split_store8(av,     &Ash[sr][kh],     &Asl[sr][kh]);
        split_store8(av + 8, &Ash[sr][kh + 8], &Asl[sr][kh + 8]);
        *reinterpret_cast<uint4*>(&Bsh[sr][kh])     = bh0;
        *reinterpret_cast<uint4*>(&Bsh[sr][kh + 8]) = bh1;
        *reinterpret_cast<uint4*>(&Bsl[sr][kh])     = bl0;
        *reinterpret_cast<uint4*>(&Bsl[sr][kh + 8]) = bl1;
        __syncthreads();   // tile staged

        bf16x8 afh[4], afl[4], bfh[4], bfl[4];
#pragma unroll
        for (int i = 0; i < 4; ++i) {
            afh[i] = *reinterpret_cast<const bf16x8*>(&Ash[wr * 64 + i * 16 + lr][ks]);
            afl[i] = *reinterpret_cast<const bf16x8*>(&Asl[wr * 64 + i * 16 + lr][ks]);
            bfh[i] = *reinterpret_cast<const bf16x8*>(&Bsh[wc * 64 + i * 16 + lr][ks]);
            bfl[i] = *reinterpret_cast<const bf16x8*>(&Bsl[wc * 64 + i * 16 + lr][ks]);
        }
#pragma unroll
        for (int mi = 0; mi < 4; ++mi)
#pragma unroll
        for (int ni = 0; ni < 4; ++ni) {
            acc[mi][ni] = __builtin_amdgcn_mfma_f32_16x16x32_bf16(afh[mi], bfh[ni], acc[mi][ni], 0, 0, 0);
            acc[mi][ni] = __builtin_amdgcn_mfma_f32_16x16x32_bf16(afh[mi], bfl[ni], acc[mi][ni], 0, 0, 0);
            acc[mi][ni] = __builtin_amdgcn_mfma_f32_16x16x32_bf16(afl[mi], bfh[ni], acc[mi][ni], 0, 0, 0);
        }
    }

    // epilogue: C/D layout col=lane&15, row=(lane>>4)*4+q
#pragma unroll
    for (int ni = 0; ni < 4; ++ni) {
        const int col = n0 + wc * 64 + ni * 16 + lr;
        const float bb = bias[col];
#pragma unroll
        for (int mi = 0; mi < 4; ++mi) {
            const int row0 = m0 + wr * 64 + mi * 16 + (lane >> 4) * 4;
#pragma unroll
            for (int q = 0; q < 4; ++q) {
                size_t off = (size_t)(row0 + q) * NSIZE + col;
                float o = acc[mi][ni][q] + bb;
                if constexpr (RES) o += res[off];
                if constexpr (RELU) o = fmaxf(o, 0.f);
                C[off] = o;
            }
        }
    }
}

// deterministic 32-dot, identical accumulation order in both passes
static __device__ __forceinline__ float dot32(const float* __restrict__ q,
                                              const float* __restrict__ k) {
    float a = 0.f, b = 0.f;
#pragma unroll
    for (int d = 0; d < 32; d += 2) {
        a = fmaf(q[d],     k[d],     a);
        b = fmaf(q[d + 1], k[d + 1], b);
    }
    return a + b;
}

// ---------------- attention (R6-proven): one wave per (b,h); K/V staged in LDS ----
__global__ __launch_bounds__(64) void k_attn(const float* __restrict__ qkv,
                                             float* __restrict__ out) {
    __shared__ alignas(16) float ks[NNODE * 32];
    __shared__ alignas(16) float vs[NNODE * 32];
    const int b    = blockIdx.x >> 3;
    const int h    = blockIdx.x & 7;
    const int lane = threadIdx.x;
    const float* __restrict__ base = qkv + (size_t)b * NNODE * 768 + h * DHEAD;

    for (int idx = lane; idx < NNODE * 8; idx += 64) {
        int j = idx >> 3, c = idx & 7;
        float4 kv = *reinterpret_cast<const float4*>(base + (size_t)j * 768 + 256 + c * 4);
        float4 vv = *reinterpret_cast<const float4*>(base + (size_t)j * 768 + 512 + c * 4);
        *reinterpret_cast<float4*>(&ks[j * 32 + c * 4]) = kv;
        *reinterpret_cast<float4*>(&vs[j * 32 + c * 4]) = vv;
    }
    __syncthreads();

    const int  i1   = lane;
    const bool has2 = lane < (NNODE - 64);
    const int  i2   = has2 ? lane + 64 : 0;

    float q1[32], q2[32];
    {
        const float* p1 = base + (size_t)i1 * 768;
        const float* p2 = base + (size_t)i2 * 768;
#pragma unroll
        for (int c = 0; c < 8; ++c) {
            float4 a = *reinterpret_cast<const float4*>(p1 + c * 4);
            float4 e = *reinterpret_cast<const float4*>(p2 + c * 4);
            q1[4 * c + 0] = a.x; q1[4 * c + 1] = a.y; q1[4 * c + 2] = a.z; q1[4 * c + 3] = a.w;
            q2[4 * c + 0] = e.x; q2[4 * c + 1] = e.y; q2[4 * c + 2] = e.z; q2[4 * c + 3] = e.w;
        }
    }
    constexpr float scale = 0.17677669529663687f;

    float m1 = -INFINITY, m2 = -INFINITY;
    for (int j = 0; j < NNODE; ++j) {
        const float* kp = &ks[j * 32];
        float kk[32];
#pragma unroll
        for (int c = 0; c < 8; ++c) {
            float4 kv = *reinterpret_cast<const float4*>(kp + c * 4);
            kk[4 * c + 0] = kv.x; kk[4 * c + 1] = kv.y; kk[4 * c + 2] = kv.z; kk[4 * c + 3] = kv.w;
        }
        m1 = fmaxf(m1, dot32(q1, kk) * scale);
        m2 = fmaxf(m2, dot32(q2, kk) * scale);
    }

    float l1 = 0.f, l2 = 0.f;
    float o1[32] = {}, o2[32] = {};
    for (int j = 0; j < NNODE; ++j) {
        const float* kp = &ks[j * 32];
        const float* vp = &vs[j * 32];
        float kk[32];
#pragma unroll
        for (int c = 0; c < 8; ++c) {
            float4 kv = *reinterpret_cast<const float4*>(kp + c * 4);
            kk[4 * c + 0] = kv.x; kk[4 * c + 1] = kv.y; kk[4 * c + 2] = kv.z; kk[4 * c + 3] = kv.w;
        }
        float s1 = dot32(q1, kk) * scale;
        float s2 = dot32(q2, kk) * scale;
        float p1 = __expf(s1 - m1);
        float p2 = __expf(s2 - m2);
        l1 += p1;
        l2 += p2;
#pragma unroll
        for (int c = 0; c < 8; ++c) {
            float4 vv = *reinterpret_cast<const float4*>(vp + c * 4);
            o1[4 * c + 0] = fmaf(p1, vv.x, o1[4 * c + 0]);
            o1[4 * c + 1] = fmaf(p1, vv.y, o1[4 * c + 1]);
            o1[4 * c + 2] = fmaf(p1, vv.z, o1[4 * c + 2]);
            o1[4 * c + 3] = fmaf(p1, vv.w, o1[4 * c + 3]);
            o2[4 * c + 0] = fmaf(p2, vv.x, o2[4 * c + 0]);
            o2[4 * c + 1] = fmaf(p2, vv.y, o2[4 * c + 1]);
            o2[4 * c + 2] = fmaf(p2, vv.z, o2[4 * c + 2]);
            o2[4 * c + 3] = fmaf(p2, vv.w, o2[4 * c + 3]);
        }
    }

    const float inv1 = 1.f / l1;
    float* op1 = out + ((size_t)b * NNODE + i1) * 768 + h * DHEAD;
#pragma unroll
    for (int c = 0; c < 8; ++c) {
        float4 w = make_float4(o1[4 * c + 0] * inv1, o1[4 * c + 1] * inv1,
                               o1[4 * c + 2] * inv1, o1[4 * c + 3] * inv1);
        *reinterpret_cast<float4*>(op1 + c * 4) = w;
    }
    if (has2) {
        const float inv2 = 1.f / l2;
        float* op2 = out + ((size_t)b * NNODE + i2) * 768 + h * DHEAD;
#pragma unroll
        for (int c = 0; c < 8; ++c) {
            float4 w = make_float4(o2[4 * c + 0] * inv2, o2[4 * c + 1] * inv2,
                                   o2[4 * c + 2] * inv2, o2[4 * c + 3] * inv2);
            *reinterpret_cast<float4*>(op2 + c * 4) = w;
        }
    }
}

// ---------------- in-place LayerNorm over H=256, one wave per row ----------------
__global__ __launch_bounds__(256) void k_ln(float* __restrict__ x, const float* __restrict__ sc,
                                            const float* __restrict__ bp) {
    const int row = blockIdx.x * 4 + (threadIdx.x >> 6);
    const int lane = threadIdx.x & 63;
    float* rp = &x[(size_t)row * HDIM + lane * 4];
    float4 v = *reinterpret_cast<const float4*>(rp);
    float mean = wave_sum(v.x + v.y + v.z + v.w) * (1.f / 256.f);
    float d0 = v.x - mean, d1 = v.y - mean, d2 = v.z - mean, d3 = v.w - mean;
    float var = wave_sum(d0 * d0 + d1 * d1 + d2 * d2 + d3 * d3) * (1.f / 256.f);
    float inv = 1.f / sqrtf(var + 1e-5f);
    float4 sv = *reinterpret_cast<const float4*>(&sc[lane * 4]);
    float4 bv = *reinterpret_cast<const float4*>(&bp[lane * 4]);
    float4 ov;
    ov.x = fmaf(d0 * inv, sv.x, bv.x);
    ov.y = fmaf(d1 * inv, sv.y, bv.y);
    ov.z = fmaf(d2 * inv, sv.z, bv.z);
    ov.w = fmaf(d3 * inv, sv.w, bv.w);
    *reinterpret_cast<float4*>(rp) = ov;
}

// ---------------- Gram: S[b] = x[b] @ x[b]^T  (one block per batch, pure f32) -----
__global__ __launch_bounds__(256) void k_gram(const float* __restrict__ x, float* __restrict__ S) {
    __shared__ alignas(16) float xs[16][128];
    const int b = blockIdx.x;
    const int t = threadIdx.x, tx = t & 15, ty = t >> 4;
    const int li = t >> 1, lko = (t & 1) * 8;
    float acc[8][8] = {};
    for (int kc = 0; kc < HDIM; kc += 16) {
        float va[8] = {0.f, 0.f, 0.f, 0.f, 0.f, 0.f, 0.f, 0.f};
        if (li < NNODE) {
            const float* p = &x[((size_t)b * NNODE + li) * HDIM + kc + lko];
            float4 u0 = *reinterpret_cast<const float4*>(p);
            float4 u1 = *reinterpret_cast<const float4*>(p + 4);
            va[0] = u0.x; va[1] = u0.y; va[2] = u0.z; va[3] = u0.w;
            va[4] = u1.x; va[5] = u1.y; va[6] = u1.z; va[7] = u1.w;
        }
        __syncthreads();
#pragma unroll
        for (int m = 0; m < 8; ++m) xs[lko + m][li] = va[m];
        __syncthreads();
#pragma unroll
        for (int k = 0; k < 16; ++k) {
            float ai[8], bj[8];
#pragma unroll
            for (int a = 0; a < 8; ++a) ai[a] = xs[k][ty + 16 * a];
#pragma unroll
            for (int c = 0; c < 8; ++c) bj[c] = xs[k][tx + 16 * c];
#pragma unroll
            for (int a = 0; a < 8; ++a)
#pragma unroll
                for (int c = 0; c < 8; ++c)
                    acc[a][c] = fmaf(ai[a], bj[c], acc[a][c]);
        }
    }
#pragma unroll
    for (int a = 0; a < 8; ++a) {
        int i = ty + 16 * a;
        if (i < NNODE) {
#pragma unroll
            for (int c = 0; c < 8; ++c) {
                int j = tx + 16 * c;
                if (j < NNODE) S[(size_t)b * NNODE * NNODE + (size_t)i * NNODE + j] = acc[a][c];
            }
        }
    }
}

// ---------------- routing decode: DPP-accelerated merged reduction ----------------
// Levels 1,2 = quad_perm (exact xor); 4,8 = row_ror (rotation reduce — valid since the
// merge is commutative+associative; lane-sets stay disjoint); 16 = ds_swizzle xor16;
// 32 = __shfl_xor. Only 2 LDS-latency levels remain (was 6). Argmax compare/tie-break
// identical to the proven code -> route bits identical.
#define RLEVEL(GETF, GETI)                                                      \
    {                                                                           \
        float key2  = GETF(key);  int idx2 = GETI(idx);                         \
        float msel2 = GETF(msel); float dsel2 = GETF(dsel);                     \
        float mm2   = GETF(m);    float ss2  = GETF(sum);                       \
        if (key2 > key || (key2 == key && idx2 < idx)) {                        \
            key = key2; idx = idx2; msel = msel2; dsel = dsel2;                 \
        }                                                                       \
        float mn = fmaxf(m, mm2);                                               \
        sum = sum * __expf(m - mn) + ss2 * __expf(mm2 - mn);                    \
        m = mn;                                                                 \
    }

__global__ __launch_bounds__(64, 1) void k_route(const float* __restrict__ S,
                                                 const float* __restrict__ demand,
                                                 const float* __restrict__ capacity,
                                                 const float* __restrict__ gumbel,
                                                 float* __restrict__ out, int nsteps) {
    __shared__ alignas(16) float Sl[NNODE * NNODE];   // 40 KB
    const int b = blockIdx.x;
    const int lane = threadIdx.x;
    const float* Sb = S + (size_t)b * NNODE * NNODE;
    for (int i = lane; i < NNODE * NNODE / 4; i += 64)
        *reinterpret_cast<float4*>(&Sl[i * 4]) = *reinterpret_cast<const float4*>(&Sb[i * 4]);
    __syncthreads();

    const int j1 = lane, j2 = lane + 64;
    const bool v2 = (j2 < NNODE);
    const float d1 = demand[(size_t)b * NNODE + j1];
    const float d2 = v2 ? demand[(size_t)b * NNODE + j2] : 0.f;
    bool vis1 = (j1 == 0), vis2 = false;
    float cap = capacity[b];
    int cur = 0;
    float lp = 0.f;
    float* route = out + (size_t)b * RLEN;
    if (lane == 0) route[0] = 0.f;

    float g1 = gumbel[(size_t)b * NNODE + j1];
    float g2 = v2 ? gumbel[(size_t)b * NNODE + j2] : 0.f;

    for (int s = 0; s < nsteps; ++s) {
        float ng1 = 0.f, ng2 = 0.f;
        if (s + 1 < nsteps) {   // next step's gumbel issues now; hides under this step
            const float* gn = gumbel + ((size_t)(s + 1) * BATCH + b) * NNODE;
            ng1 = gn[j1];
            ng2 = v2 ? gn[j2] : 0.f;
        }
        bool f1 = (!vis1) && (d1 <= cap);
        bool f2 = v2 && (!vis2) && (d2 <= cap);
        if (__ballot(f1 || f2) == 0ULL) {
            if (lane == 0) route[1 + s] = 0.f;
            g1 = ng1; g2 = ng2;
            continue;
        }
        const float* sr = &Sl[cur * NNODE];
        float m1 = f1 ? sr[j1] : -1e9f;
        float m2 = f2 ? sr[j2] : -1e9f;
        // local combine of (j1, j2): identical tie-break (prefer lower index)
        float k1 = m1 + g1;
        float k2 = v2 ? (m2 + g2) : -INFINITY;
        float key, msel, dsel;
        int idx;
        if (k1 >= k2) { key = k1; idx = j1; msel = m1; dsel = d1; }
        else          { key = k2; idx = j2; msel = m2; dsel = d2; }
        float m = fmaxf(m1, m2);
        float sum = __expf(m1 - m) + (v2 ? __expf(m2 - m) : 0.f);
        // merged reduce: 4 VALU-latency DPP levels + 2 LDS-latency levels
        RLEVEL(fdpp<0xB1>, idpp<0xB1>);     // xor 1 (quad_perm 1,0,3,2)
        RLEVEL(fdpp<0x4E>, idpp<0x4E>);     // xor 2 (quad_perm 2,3,0,1)
        RLEVEL(fdpp<0x124>, idpp<0x124>);   // row_ror:4
        RLEVEL(fdpp<0x128>, idpp<0x128>);   // row_ror:8
        RLEVEL(fswz16, iswz16);             // xor 16 (ds_swizzle 0x401F)
#define SH32F(v) __shfl_xor(v, 32)
#define SH32I(v) __shfl_xor(v, 32)
        RLEVEL(SH32F, SH32I);               // xor 32
#undef SH32F
#undef SH32I
        const int choice = idx;   // uniform across wave
        lp += msel - m - __logf(sum);
        if (j1 == choice) vis1 = true;
        if (j2 == choice) vis2 = true;
        cap -= dsel;
        cur = choice;
        if (lane == 0) route[1 + s] = (float)choice;
        g1 = ng1; g2 = ng2;
    }
    if (lane == 0) out[(size_t)BATCH * RLEN + b] = lp;
}

extern "C" void kernel_launch(void* const* d_in, const int* in_sizes, int n_in,
                              void* d_out, int out_size, void* d_ws, size_t ws_size,
                              hipStream_t stream) {
    const float* node_feats = (const float*)d_in[0];
    const float* demand     = (const float*)d_in[1];
    const float* capacity   = (const float*)d_in[2];
    const float* gumbel     = (const float*)d_in[3];
    const float* W_node     = (const float*)d_in[4];
    const float* b_node     = (const float*)d_in[5];
    const float* qkv_w      = (const float*)d_in[6];
    const float* qkv_b      = (const float*)d_in[7];
    const float* out_w      = (const float*)d_in[8];
    const float* out_b      = (const float*)d_in[9];
    const float* ln1_s      = (const float*)d_in[10];
    const float* ln1_b      = (const float*)d_in[11];
    const float* w1         = (const float*)d_in[12];
    const float* b1         = (const float*)d_in[13];
    const float* w2         = (const float*)d_in[14];
    const float* b2         = (const float*)d_in[15];
    const float* ln2_s      = (const float*)d_in[16];
    const float* ln2_b      = (const float*)d_in[17];
    const int gsteps = in_sizes[3] / (BATCH * NNODE);   // 199

    float* x    = (float*)d_ws;                       // [MTOK][256]  52 MB
    float* buf1 = x + (size_t)MTOK * HDIM;            // [MTOK][768]  157 MB
    float* S    = buf1;                               // reuse after encoder
    // pre-split transposed weights at ws tail (+6.3 MB)
    u16* qkvTh = (u16*)(buf1 + (size_t)MTOK * 768);
    u16* qkvTl = qkvTh + (size_t)3 * 768 * 256;
    u16* prjTh = qkvTl + (size_t)3 * 768 * 256;
    u16* prjTl = prjTh + (size_t)3 * 256 * 256;
    u16* f1Th  = prjTl + (size_t)3 * 256 * 256;
    u16* f1Tl  = f1Th  + (size_t)3 * 512 * 256;
    u16* f2Th  = f1Tl  + (size_t)3 * 512 * 256;
    u16* f2Tl  = f2Th  + (size_t)3 * 256 * 512;
    float* out = (float*)d_out;

    // one-time weight splits (per launch; deterministic)
    k_wsplit<<<dim3((768 * 32 + 255) / 256, 3), 256, 0, stream>>>(qkv_w, qkvTh, qkvTl, 256, 768);
    k_wsplit<<<dim3((256 * 32 + 255) / 256, 3), 256, 0, stream>>>(out_w, prjTh, prjTl, 256, 256);
    k_wsplit<<<dim3((512 * 32 + 255) / 256, 3), 256, 0, stream>>>(w1, f1Th, f1Tl, 256, 512);
    k_wsplit<<<dim3((256 * 64 + 255) / 256, 3), 256, 0, stream>>>(w2, f2Th, f2Tl, 512, 256);

    k_embed<<<MTOK * HDIM / 256, 256, 0, stream>>>(node_feats, W_node, b_node, x);

    for (int l = 0; l < NLAYER; ++l) {
        // qkv = x @ qkv_w + qkv_b            [MTOK,768]
        k_mfma<256, 768, false, false><<<dim3(6, MTOK / 128), 256, 0, stream>>>(
            x, 256, qkvTh + (size_t)l * 768 * 256, qkvTl + (size_t)l * 768 * 256,
            qkv_b + (size_t)l * 768, nullptr, buf1);
        // attention (o written into q-slice of buf1, row stride 768)
        k_attn<<<BATCH * NHEAD, 64, 0, stream>>>(buf1, buf1);
        // x = x + o @ out_w + out_b
        k_mfma<256, 256, false, true><<<dim3(2, MTOK / 128), 256, 0, stream>>>(
            buf1, 768, prjTh + (size_t)l * 256 * 256, prjTl + (size_t)l * 256 * 256,
            out_b + (size_t)l * 256, x, x);
        k_ln<<<MTOK / 4, 256, 0, stream>>>(x, ln1_s + (size_t)l * 256, ln1_b + (size_t)l * 256);
        // h = relu(x @ w1 + b1)              [MTOK,512]
        k_mfma<256, 512, true, false><<<dim3(4, MTOK / 128), 256, 0, stream>>>(
            x, 256, f1Th + (size_t)l * 512 * 256, f1Tl + (size_t)l * 512 * 256,
            b1 + (size_t)l * 512, nullptr, buf1);
        // x = x + h @ w2 + b2
        k_mfma<512, 256, false, true><<<dim3(2, MTOK / 128), 256, 0, stream>>>(
            buf1, 512, f2Th + (size_t)l * 256 * 512, f2Tl + (size_t)l * 256 * 512,
            b2 + (size_t)l * 256, x, x);
        k_ln<<<MTOK / 4, 256, 0, stream>>>(x, ln2_s + (size_t)l * 256, ln2_b + (size_t)l * 256);
    }

    k_gram<<<BATCH, 256, 0, stream>>>(x, S);
    k_route<<<BATCH, 64, 0, stream>>>(S, demand, capacity, gumbel, out, gsteps);
    (void)n_in; (void)out_size; (void)ws_size;
}